// Round 4
// baseline (1755.420 us; speedup 1.0000x reference)
//
#include <hip/hip_runtime.h>
#include <hip/hip_bf16.h>

#define HID 128
#define SEQ 2048
#define BATCH 64
#define NOUT 512

typedef __attribute__((ext_vector_type(8))) short bf16x8;
typedef __attribute__((ext_vector_type(4))) float f32x4;

__device__ __forceinline__ short f2bf(float f) {
    unsigned u = __float_as_uint(f);
    unsigned r = u + 0x7fffu + ((u >> 16) & 1u);   // RNE
    return (short)(r >> 16);
}

__device__ __forceinline__ float fast_sigmoid(float x) {
    return 1.0f / (1.0f + __expf(-x));
}

__device__ __forceinline__ float fast_tanh(float x) {
    return 1.0f - 2.0f / (__expf(2.0f * x) + 1.0f);
}

// ---------------------------------------------------------------------------
// MFMA GRU recurrence. 8 blocks x 8 batches; 512 threads = 8 waves.
// Per step: G[8 x 384] = H[8 x 128] @ W_hh^T via 96 mfma_16x16x32_bf16
// (466 CU-cyc at the 4.85 cyc/MFMA ceiling) instead of ~1340 VALU-busy
// cycles (rounds 1-3 showed a structural ~2x AGPR-operand tax on the VALU
// path that HIP-level pinning cannot remove; round-3 asm pinning made it
// WORSE by inserting accvgpr_read copies).
//
// Wave j owns n-tiles {j, j+8, j+16}: r/z/n gates for a given h land in the
// SAME lane & acc reg (D: batch = lane&15 [second operand's 16-axis],
// n-in-tile = (lane>>4)*4 + reg [first operand's 16-axis] -- mapping reused
// verbatim from the harness-PASSING proj_mfma kernel).
//   - W fragments live in registers (AGPR-parking is fine: MFMA reads AGPRs
//     natively -- that's the whole point of this pipe switch).
//   - H: bf16 in LDS, double-buffered, 16B-block XOR swizzle (u ^= row&7)
//     -> conflict-free ds_read_b128 frag loads AND packed ds_write_b32.
//   - M=8 leaves D rows 8-15 garbage: one __shfl_xor(.,8) per gate moves
//     regs 2-3 to the upper half-wave so EVERY lane does 2 activations
//     (halves the trans-pipe load to ~192 cyc/SIMD, below the MFMA floor).
//   - hold (f32 h) register-carried; one raw s_barrier + lgkmcnt(0)/step.
// ---------------------------------------------------------------------------
__global__ __launch_bounds__(512, 2) void gru_seq(
    const float* __restrict__ latent,   // [BATCH][HID]
    const float* __restrict__ W_hh,     // [3*HID][HID]
    const float* __restrict__ b_ih,     // [3*HID]
    const float* __restrict__ b_hh,     // [3*HID]
    __hip_bfloat16* __restrict__ hs)    // [BATCH][SEQ][HID]  (bf16)
{
    const int tid  = threadIdx.x;          // 0..511
    const int j    = tid >> 6;             // wave 0..7 -> n-tiles {j,j+8,j+16}
    const int lane = tid & 63;
    const int rr   = lane & 15;            // operand 16-axis / D batch col
    const int g    = lane >> 4;            // 0..3
    const int hi   = (lane >> 3) & 1;      // upper half of 16-group
    const int br   = rr & 7;               // batch row 0..7
    const int h0   = 16 * j + 4 * g + 2 * hi;  // this lane's 2 h columns

    // [2 buffers][16 rows][128 cols] bf16, 16B-block swizzled within rows
    __shared__ __align__(16) __hip_bfloat16 Hl[2][2048];

    // ---- W fragments: lane holds W_hh[16T + rr][kt*32 + g*8 .. +7] ----
    bf16x8 wfr[3][4];
    #pragma unroll
    for (int tt = 0; tt < 3; tt++) {
        const int T = j + 8 * tt;
        #pragma unroll
        for (int kt = 0; kt < 4; kt++) {
            const float* wp = W_hh + (size_t)(T * 16 + rr) * HID + kt * 32 + g * 8;
            float4 x = *(const float4*)wp;
            float4 y = *(const float4*)(wp + 4);
            bf16x8 f;
            f[0] = f2bf(x.x); f[1] = f2bf(x.y); f[2] = f2bf(x.z); f[3] = f2bf(x.w);
            f[4] = f2bf(y.x); f[5] = f2bf(y.y); f[6] = f2bf(y.z); f[7] = f2bf(y.w);
            wfr[tt][kt] = f;
        }
    }

    // ---- biases for this lane's 2 h positions ----
    const float2 bir = *(const float2*)&b_ih[h0];
    const float2 biz = *(const float2*)&b_ih[HID + h0];
    const float2 bin2 = *(const float2*)&b_ih[2 * HID + h0];
    const float2 bhr = *(const float2*)&b_hh[h0];
    const float2 bhz = *(const float2*)&b_hh[HID + h0];
    const float2 bhn2 = *(const float2*)&b_hh[2 * HID + h0];
    const float cr0 = bir.x + bhr.x, cr1 = bir.y + bhr.y;
    const float cz0 = biz.x + bhz.x, cz1 = biz.y + bhz.y;
    const float bn0 = bin2.x, bn1 = bin2.y;
    const float hb0 = bhn2.x, hb1 = bhn2.y;

    // ---- swizzled LDS element offsets (lane constants) ----
    // read frag kt: row rr, 16B-block u = (kt*4+g) ^ (rr&7)
    const int re0 = rr * 128 + (((0 * 4 + g) ^ (rr & 7)) << 3);
    const int re1 = rr * 128 + (((1 * 4 + g) ^ (rr & 7)) << 3);
    const int re2 = rr * 128 + (((2 * 4 + g) ^ (rr & 7)) << 3);
    const int re3 = rr * 128 + (((3 * 4 + g) ^ (rr & 7)) << 3);
    // write: row br, cols h0..h0+1 -> block (2j + (g>>1)) ^ br, sub 4(g&1)+2hi
    const int we = br * 128 + ((((2 * j) + (g >> 1)) ^ br) << 3)
                 + 4 * (g & 1) + 2 * hi;

    // ---- init: hold regs + H buffer 0 (+ zero rows 8-15, both buffers) ----
    const int batch = blockIdx.x * 8 + br;
    float2 h02 = *(const float2*)&latent[batch * HID + h0];
    float hold0 = h02.x, hold1 = h02.y;
    {
        unsigned v = (unsigned short)f2bf(hold0)
                   | ((unsigned)(unsigned short)f2bf(hold1) << 16);
        *(unsigned*)&Hl[0][we] = v;
        // rows 8-15 of both buffers = 0 (garbage MFMA rows stay finite)
        unsigned* hw = (unsigned*)&Hl[0][0];   // 2048 uints total
        for (int i = tid; i < 1024; i += 512)
            hw[512 + (i & 511) + (i >> 9) * 1024] = 0u;
    }
    __syncthreads();

    __hip_bfloat16* op = hs + ((size_t)batch * SEQ) * HID + h0;

    int p = 0;
    for (int t = 0; t < SEQ; t++) {
        // H fragments (conflict-free swizzled ds_read_b128)
        const __hip_bfloat16* hb = &Hl[p][0];
        bf16x8 hf0 = *(const bf16x8*)&hb[re0];
        bf16x8 hf1 = *(const bf16x8*)&hb[re1];
        bf16x8 hf2 = *(const bf16x8*)&hb[re2];
        bf16x8 hf3 = *(const bf16x8*)&hb[re3];

        f32x4 a0 = {0.f, 0.f, 0.f, 0.f};   // r-gate tile j
        f32x4 a1 = {0.f, 0.f, 0.f, 0.f};   // z-gate tile j+8
        f32x4 a2 = {0.f, 0.f, 0.f, 0.f};   // n-gate tile j+16
        a0 = __builtin_amdgcn_mfma_f32_16x16x32_bf16(wfr[0][0], hf0, a0, 0, 0, 0);
        a1 = __builtin_amdgcn_mfma_f32_16x16x32_bf16(wfr[1][0], hf0, a1, 0, 0, 0);
        a2 = __builtin_amdgcn_mfma_f32_16x16x32_bf16(wfr[2][0], hf0, a2, 0, 0, 0);
        a0 = __builtin_amdgcn_mfma_f32_16x16x32_bf16(wfr[0][1], hf1, a0, 0, 0, 0);
        a1 = __builtin_amdgcn_mfma_f32_16x16x32_bf16(wfr[1][1], hf1, a1, 0, 0, 0);
        a2 = __builtin_amdgcn_mfma_f32_16x16x32_bf16(wfr[2][1], hf1, a2, 0, 0, 0);
        a0 = __builtin_amdgcn_mfma_f32_16x16x32_bf16(wfr[0][2], hf2, a0, 0, 0, 0);
        a1 = __builtin_amdgcn_mfma_f32_16x16x32_bf16(wfr[1][2], hf2, a1, 0, 0, 0);
        a2 = __builtin_amdgcn_mfma_f32_16x16x32_bf16(wfr[2][2], hf2, a2, 0, 0, 0);
        a0 = __builtin_amdgcn_mfma_f32_16x16x32_bf16(wfr[0][3], hf3, a0, 0, 0, 0);
        a1 = __builtin_amdgcn_mfma_f32_16x16x32_bf16(wfr[1][3], hf3, a1, 0, 0, 0);
        a2 = __builtin_amdgcn_mfma_f32_16x16x32_bf16(wfr[2][3], hf3, a2, 0, 0, 0);

        // rebalance: upper half-wave (hi=1) adopts regs 2,3 from lane^8
        float s02 = __shfl_xor(a0[2], 8), s03 = __shfl_xor(a0[3], 8);
        float s12 = __shfl_xor(a1[2], 8), s13 = __shfl_xor(a1[3], 8);
        float s22 = __shfl_xor(a2[2], 8), s23 = __shfl_xor(a2[3], 8);
        float gr0 = hi ? s02 : a0[0], gr1 = hi ? s03 : a0[1];
        float gz0 = hi ? s12 : a1[0], gz1 = hi ? s13 : a1[1];
        float gn0 = hi ? s22 : a2[0], gn1 = hi ? s23 : a2[1];

        // activations (2 h positions per lane), exact same math as before
        float r0 = fast_sigmoid(cr0 + gr0);
        float z0 = fast_sigmoid(cz0 + gz0);
        float n0 = fast_tanh(bn0 + r0 * (gn0 + hb0));
        float hn0 = (1.0f - z0) * n0 + z0 * hold0;
        hold0 = hn0;
        float r1 = fast_sigmoid(cr1 + gr1);
        float z1 = fast_sigmoid(cz1 + gz1);
        float n1 = fast_tanh(bn1 + r1 * (gn1 + hb1));
        float hn1 = (1.0f - z1) * n1 + z1 * hold1;
        hold1 = hn1;

        unsigned v = (unsigned short)f2bf(hn0)
                   | ((unsigned)(unsigned short)f2bf(hn1) << 16);
        *(unsigned*)&Hl[p ^ 1][we] = v;    // next step's H (swizzled slot)
        *(unsigned*)op = v;                // history output (not drained)
        op += HID;

        // LDS-only drain + raw barrier: global stores stay in flight
        asm volatile("s_waitcnt lgkmcnt(0)" ::: "memory");
        __builtin_amdgcn_s_barrier();
        asm volatile("" ::: "memory");
        p ^= 1;
    }
}

// ---------------------------------------------------------------------------
// Repack fc_W (f32 [512][128]) into bf16 MFMA fragment order:
//   wfrag[((ct*4 + q)*64 + lane)*8 + j] = bf16(fc_W[ct*16 + (lane&15)]
//                                                  [q*32 + (lane>>4)*8 + j])
// ---------------------------------------------------------------------------
__global__ void wprep(const float* __restrict__ fc_W,
                      __hip_bfloat16* __restrict__ wfrag)
{
    int t = blockIdx.x * 256 + threadIdx.x;      // 0..65535
    int j    = t & 7;
    int lane = (t >> 3) & 63;
    int q    = (t >> 9) & 3;
    int ct   = t >> 11;
    int n = ct * 16 + (lane & 15);
    int k = q * 32 + (lane >> 4) * 8 + j;
    unsigned short v = (unsigned short)f2bf(fc_W[n * HID + k]);
    wfrag[t] = __builtin_bit_cast(__hip_bfloat16, v);
}

// ---------------------------------------------------------------------------
// Projection: out[row][o] = sum_k hs[row][k] * fc_W[o][k] + fc_b[o]
// M = 131072, N = 512, K = 128. bf16 MFMA 16x16x32, operand-swapped
// (weights as first operand) -> lane's acc regs = consecutive out columns.
// ---------------------------------------------------------------------------
__global__ __launch_bounds__(256) void proj_mfma(
    const __hip_bfloat16* __restrict__ hsb,    // [M][128] bf16
    const __hip_bfloat16* __restrict__ wfrag,  // fragment-ordered [32][4][64][8]
    const float* __restrict__ fc_b,            // [512]
    float* __restrict__ out)                   // [M][512] f32
{
    const int lane = threadIdx.x & 63;
    const int wave = threadIdx.x >> 6;
    const int m    = lane & 15;
    const int quad = lane >> 4;

    const long r0 = ((long)blockIdx.x * 4 + wave) * 32;

    bf16x8 bfrag[2][4];                         // hs rows as second operand
    #pragma unroll
    for (int rt = 0; rt < 2; rt++) {
        #pragma unroll
        for (int q = 0; q < 4; q++) {
            const __hip_bfloat16* p =
                hsb + (r0 + rt * 16 + m) * HID + q * 32 + quad * 8;
            bfrag[rt][q] = *(const bf16x8*)p;   // 16B aligned
        }
    }

    for (int ct2 = 0; ct2 < 16; ct2++) {
        const int ct0 = 2 * ct2;
        f32x4 acc00 = {0.f, 0.f, 0.f, 0.f};
        f32x4 acc01 = {0.f, 0.f, 0.f, 0.f};
        f32x4 acc10 = {0.f, 0.f, 0.f, 0.f};
        f32x4 acc11 = {0.f, 0.f, 0.f, 0.f};
        #pragma unroll
        for (int q = 0; q < 4; q++) {
            bf16x8 aw0 = *(const bf16x8*)(wfrag + (((ct0)     * 4 + q) * 64 + lane) * 8);
            bf16x8 aw1 = *(const bf16x8*)(wfrag + (((ct0 + 1) * 4 + q) * 64 + lane) * 8);
            acc00 = __builtin_amdgcn_mfma_f32_16x16x32_bf16(aw0, bfrag[0][q], acc00, 0, 0, 0);
            acc01 = __builtin_amdgcn_mfma_f32_16x16x32_bf16(aw1, bfrag[0][q], acc01, 0, 0, 0);
            acc10 = __builtin_amdgcn_mfma_f32_16x16x32_bf16(aw0, bfrag[1][q], acc10, 0, 0, 0);
            acc11 = __builtin_amdgcn_mfma_f32_16x16x32_bf16(aw1, bfrag[1][q], acc11, 0, 0, 0);
        }
        const int n0 = ct0 * 16 + quad * 4;
        const float4 bias0 = *(const float4*)&fc_b[n0];
        const float4 bias1 = *(const float4*)&fc_b[n0 + 16];
        float4 o;
        float* row0 = &out[(r0 + m) * NOUT];
        float* row1 = &out[(r0 + 16 + m) * NOUT];
        o.x = acc00[0] + bias0.x; o.y = acc00[1] + bias0.y;
        o.z = acc00[2] + bias0.z; o.w = acc00[3] + bias0.w;
        *(float4*)&row0[n0] = o;
        o.x = acc01[0] + bias1.x; o.y = acc01[1] + bias1.y;
        o.z = acc01[2] + bias1.z; o.w = acc01[3] + bias1.w;
        *(float4*)&row0[n0 + 16] = o;
        o.x = acc10[0] + bias0.x; o.y = acc10[1] + bias0.y;
        o.z = acc10[2] + bias0.z; o.w = acc10[3] + bias0.w;
        *(float4*)&row1[n0] = o;
        o.x = acc11[0] + bias1.x; o.y = acc11[1] + bias1.y;
        o.z = acc11[2] + bias1.z; o.w = acc11[3] + bias1.w;
        *(float4*)&row1[n0 + 16] = o;
    }
}

extern "C" void kernel_launch(void* const* d_in, const int* in_sizes, int n_in,
                              void* d_out, int out_size, void* d_ws, size_t ws_size,
                              hipStream_t stream) {
    const float* latent = (const float*)d_in[0];   // (64,128)
    const float* W_hh   = (const float*)d_in[1];   // (384,128)
    const float* b_ih   = (const float*)d_in[2];   // (384,)
    const float* b_hh   = (const float*)d_in[3];   // (384,)
    const float* fc_W   = (const float*)d_in[4];   // (512,128)
    const float* fc_b   = (const float*)d_in[5];   // (512,)
    float* out = (float*)d_out;                    // (64,2048,512)

    __hip_bfloat16* hsb   = (__hip_bfloat16*)d_ws;                   // 33.5 MB
    __hip_bfloat16* wfrag = (__hip_bfloat16*)((char*)d_ws + (size_t)BATCH * SEQ * HID * 2);

    wprep<<<256, 256, 0, stream>>>(fc_W, wfrag);
    gru_seq<<<8, 512, 0, stream>>>(latent, W_hh, b_ih, b_hh, hsb);

    const int M = BATCH * SEQ;                     // 131072
    proj_mfma<<<M / 128, 256, 0, stream>>>(hsb, wfrag, fc_b, out);
}

// Round 6
// 1700.869 us; speedup vs baseline: 1.0321x; 1.0321x over previous
//
#include <hip/hip_runtime.h>
#include <hip/hip_bf16.h>

#define HID 128
#define SEQ 2048
#define BATCH 64
#define NOUT 512

typedef __attribute__((ext_vector_type(8))) short bf16x8;
typedef __attribute__((ext_vector_type(4))) float f32x4;

__device__ __forceinline__ short f2bf(float f) {
    unsigned u = __float_as_uint(f);
    unsigned r = u + 0x7fffu + ((u >> 16) & 1u);   // RNE
    return (short)(r >> 16);
}

__device__ __forceinline__ float fast_sigmoid(float x) {
    return 1.0f / (1.0f + __expf(-x));
}

__device__ __forceinline__ float fast_tanh(float x) {
    return 1.0f - 2.0f / (__expf(2.0f * x) + 1.0f);
}

// lane ^ 8 within each 16-lane row: DPP ROW_ROR:8 (0x121 + 7).
// Replaces __shfl_xor(.,8): that lowered to ds_bpermute (DS pipe, ~120cyc
// latency on the activation critical path, and was the source of the
// 2^21 SQ_LDS_BANK_CONFLICT cycles in round 4). DPP is VALU, ~2cyc.
__device__ __forceinline__ float dpp_ror8(float x) {
    int y = __builtin_amdgcn_update_dpp(0, __builtin_bit_cast(int, x),
                                        0x128, 0xF, 0xF, true);
    return __builtin_bit_cast(float, y);
}

// ---------------------------------------------------------------------------
// MFMA GRU recurrence. 8 blocks x 8 batches; 512 threads = 8 waves.
// Round-4 skeleton (harness-verified layout/swizzle) with three changes:
//   1. rebalance via DPP row_ror:8 instead of DS-pipe shuffles
//   2. H fragment reads exec-masked to rr<8 (rows 8-15 were zero padding
//      feeding only the discarded D columns; this halves LDS read traffic
//      32KB -> 16KB per CU-step). Zero-init of rows 8-15 deleted: stale
//      regs in masked lanes only ever reach garbage D columns.
//   3. MFMA accumulators seeded with folded biases (C-in = bias) -- the
//      activation chain starts directly from the MFMA result.
// ---------------------------------------------------------------------------
__global__ __launch_bounds__(512, 2) void gru_seq(
    const float* __restrict__ latent,   // [BATCH][HID]
    const float* __restrict__ W_hh,     // [3*HID][HID]
    const float* __restrict__ b_ih,     // [3*HID]
    const float* __restrict__ b_hh,     // [3*HID]
    __hip_bfloat16* __restrict__ hs)    // [BATCH][SEQ][HID]  (bf16)
{
    const int tid  = threadIdx.x;          // 0..511
    const int j    = tid >> 6;             // wave 0..7 -> n-tiles {j,j+8,j+16}
    const int lane = tid & 63;
    const int rr   = lane & 15;            // operand 16-axis / D batch col
    const int g    = lane >> 4;            // 0..3
    const int hi   = (lane >> 3) & 1;      // upper half of 16-group
    const int br   = rr & 7;               // batch row 0..7
    const int h0   = 16 * j + 4 * g + 2 * hi;  // this lane's 2 h columns
    const int n0l  = 16 * j + 4 * g;           // this lane's 4 gate rows

    // [2 buffers][16 rows][128 cols] bf16, 16B-block swizzled within rows
    __shared__ __align__(16) __hip_bfloat16 Hl[2][2048];

    // ---- W fragments: lane holds W_hh[16T + rr][kt*32 + g*8 .. +7] ----
    bf16x8 wfr[3][4];
    #pragma unroll
    for (int tt = 0; tt < 3; tt++) {
        const int T = j + 8 * tt;
        #pragma unroll
        for (int kt = 0; kt < 4; kt++) {
            const float* wp = W_hh + (size_t)(T * 16 + rr) * HID + kt * 32 + g * 8;
            float4 x = *(const float4*)wp;
            float4 y = *(const float4*)(wp + 4);
            bf16x8 f;
            f[0] = f2bf(x.x); f[1] = f2bf(x.y); f[2] = f2bf(x.z); f[3] = f2bf(x.w);
            f[4] = f2bf(y.x); f[5] = f2bf(y.y); f[6] = f2bf(y.z); f[7] = f2bf(y.w);
            wfr[tt][kt] = f;
        }
    }

    // ---- accumulator bias seeds (lane's 4 gate rows n0l..n0l+3) ----
    // r,z: b_ih + b_hh folded; n: b_hh only (b_in enters inside tanh arg)
    f32x4 seedR, seedZ, seedN;
    {
        float4 bi = *(const float4*)&b_ih[n0l];
        float4 bh = *(const float4*)&b_hh[n0l];
        seedR[0] = bi.x + bh.x; seedR[1] = bi.y + bh.y;
        seedR[2] = bi.z + bh.z; seedR[3] = bi.w + bh.w;
        bi = *(const float4*)&b_ih[HID + n0l];
        bh = *(const float4*)&b_hh[HID + n0l];
        seedZ[0] = bi.x + bh.x; seedZ[1] = bi.y + bh.y;
        seedZ[2] = bi.z + bh.z; seedZ[3] = bi.w + bh.w;
        bh = *(const float4*)&b_hh[2 * HID + n0l];
        seedN[0] = bh.x; seedN[1] = bh.y; seedN[2] = bh.z; seedN[3] = bh.w;
    }
    const float2 bin2 = *(const float2*)&b_ih[2 * HID + h0];
    const float bn0 = bin2.x, bn1 = bin2.y;

    // ---- swizzled LDS element offsets (lane constants, round-4-proven) ----
    const int re0 = rr * 128 + (((0 * 4 + g) ^ (rr & 7)) << 3);
    const int re1 = rr * 128 + (((1 * 4 + g) ^ (rr & 7)) << 3);
    const int re2 = rr * 128 + (((2 * 4 + g) ^ (rr & 7)) << 3);
    const int re3 = rr * 128 + (((3 * 4 + g) ^ (rr & 7)) << 3);
    const int we = br * 128 + ((((2 * j) + (g >> 1)) ^ br) << 3)
                 + 4 * (g & 1) + 2 * hi;

    // ---- init: hold regs + H buffer 0 ----
    const int batch = blockIdx.x * 8 + br;
    float2 h02 = *(const float2*)&latent[batch * HID + h0];
    float hold0 = h02.x, hold1 = h02.y;
    {
        unsigned v = (unsigned short)f2bf(hold0)
                   | ((unsigned)(unsigned short)f2bf(hold1) << 16);
        *(unsigned*)&Hl[0][we] = v;
    }
    __syncthreads();

    __hip_bfloat16* op = hs + ((size_t)batch * SEQ) * HID + h0;

    bf16x8 hf0 = {}, hf1 = {}, hf2 = {}, hf3 = {};
    int p = 0;
    for (int t = 0; t < SEQ; t++) {
        // H fragments: only rows 0-7 hold real data; mask reads to rr<8
        // (halves LDS traffic; stale hf in rr>=8 lanes feed only the
        // garbage D columns that the rebalance discards)
        const __hip_bfloat16* hb = &Hl[p][0];
        if (rr < 8) {
            hf0 = *(const bf16x8*)&hb[re0];
            hf1 = *(const bf16x8*)&hb[re1];
            hf2 = *(const bf16x8*)&hb[re2];
            hf3 = *(const bf16x8*)&hb[re3];
        }

        f32x4 a0 = seedR;   // r-gate tile j      (bias pre-seeded)
        f32x4 a1 = seedZ;   // z-gate tile j+8
        f32x4 a2 = seedN;   // n-gate tile j+16   (b_hh part)
        a0 = __builtin_amdgcn_mfma_f32_16x16x32_bf16(wfr[0][0], hf0, a0, 0, 0, 0);
        a1 = __builtin_amdgcn_mfma_f32_16x16x32_bf16(wfr[1][0], hf0, a1, 0, 0, 0);
        a2 = __builtin_amdgcn_mfma_f32_16x16x32_bf16(wfr[2][0], hf0, a2, 0, 0, 0);
        a0 = __builtin_amdgcn_mfma_f32_16x16x32_bf16(wfr[0][1], hf1, a0, 0, 0, 0);
        a1 = __builtin_amdgcn_mfma_f32_16x16x32_bf16(wfr[1][1], hf1, a1, 0, 0, 0);
        a2 = __builtin_amdgcn_mfma_f32_16x16x32_bf16(wfr[2][1], hf1, a2, 0, 0, 0);
        a0 = __builtin_amdgcn_mfma_f32_16x16x32_bf16(wfr[0][2], hf2, a0, 0, 0, 0);
        a1 = __builtin_amdgcn_mfma_f32_16x16x32_bf16(wfr[1][2], hf2, a1, 0, 0, 0);
        a2 = __builtin_amdgcn_mfma_f32_16x16x32_bf16(wfr[2][2], hf2, a2, 0, 0, 0);
        a0 = __builtin_amdgcn_mfma_f32_16x16x32_bf16(wfr[0][3], hf3, a0, 0, 0, 0);
        a1 = __builtin_amdgcn_mfma_f32_16x16x32_bf16(wfr[1][3], hf3, a1, 0, 0, 0);
        a2 = __builtin_amdgcn_mfma_f32_16x16x32_bf16(wfr[2][3], hf3, a2, 0, 0, 0);

        // rebalance: hi half adopts regs 2,3 from lane^8 -- pure VALU DPP
        float s00 = dpp_ror8(a0[2]), s01 = dpp_ror8(a0[3]);
        float s10 = dpp_ror8(a1[2]), s11 = dpp_ror8(a1[3]);
        float s20 = dpp_ror8(a2[2]), s21 = dpp_ror8(a2[3]);
        float gr0 = hi ? s00 : a0[0], gr1 = hi ? s01 : a0[1];
        float gz0 = hi ? s10 : a1[0], gz1 = hi ? s11 : a1[1];
        float gn0 = hi ? s20 : a2[0], gn1 = hi ? s21 : a2[1];

        // activations (biases already folded into the accumulators)
        float r0 = fast_sigmoid(gr0);
        float z0 = fast_sigmoid(gz0);
        float n0 = fast_tanh(bn0 + r0 * gn0);
        float hn0 = (1.0f - z0) * n0 + z0 * hold0;
        hold0 = hn0;
        float r1 = fast_sigmoid(gr1);
        float z1 = fast_sigmoid(gz1);
        float n1 = fast_tanh(bn1 + r1 * gn1);
        float hn1 = (1.0f - z1) * n1 + z1 * hold1;
        hold1 = hn1;

        unsigned v = (unsigned short)f2bf(hn0)
                   | ((unsigned)(unsigned short)f2bf(hn1) << 16);
        *(unsigned*)&Hl[p ^ 1][we] = v;    // next step's H (swizzled slot)
        *(unsigned*)op = v;                // history output (not drained)
        op += HID;

        // LDS-only drain + raw barrier: global stores stay in flight
        asm volatile("s_waitcnt lgkmcnt(0)" ::: "memory");
        __builtin_amdgcn_s_barrier();
        asm volatile("" ::: "memory");
        p ^= 1;
    }
}

// ---------------------------------------------------------------------------
// Repack fc_W (f32 [512][128]) into bf16 MFMA fragment order:
//   wfrag[((ct*4 + q)*64 + lane)*8 + j] = bf16(fc_W[ct*16 + (lane&15)]
//                                                  [q*32 + (lane>>4)*8 + j])
// ---------------------------------------------------------------------------
__global__ void wprep(const float* __restrict__ fc_W,
                      __hip_bfloat16* __restrict__ wfrag)
{
    int t = blockIdx.x * 256 + threadIdx.x;      // 0..65535
    int j    = t & 7;
    int lane = (t >> 3) & 63;
    int q    = (t >> 9) & 3;
    int ct   = t >> 11;
    int n = ct * 16 + (lane & 15);
    int k = q * 32 + (lane >> 4) * 8 + j;
    unsigned short v = (unsigned short)f2bf(fc_W[n * HID + k]);
    wfrag[t] = __builtin_bit_cast(__hip_bfloat16, v);
}

// ---------------------------------------------------------------------------
// Projection: out[row][o] = sum_k hs[row][k] * fc_W[o][k] + fc_b[o]
// M = 131072, N = 512, K = 128. bf16 MFMA 16x16x32, operand-swapped.
// proj has been stuck at ~280us vs a ~50us roofline (268MB of writes)
// for four rounds. Theory: 268MB of write-allocate churn through the
// 32MB L2. This round: NONTEMPORAL stores (nt flag, bypass L2) and
// nontemporal loads for the single-use hsb rows.
// NOTE: __builtin_nontemporal_* requires clang ext_vector types, not
// HIP_vector_type float4 -- use f32x4 throughout the store path.
// ---------------------------------------------------------------------------
__global__ __launch_bounds__(256) void proj_mfma(
    const __hip_bfloat16* __restrict__ hsb,    // [M][128] bf16
    const __hip_bfloat16* __restrict__ wfrag,  // fragment-ordered [32][4][64][8]
    const float* __restrict__ fc_b,            // [512]
    float* __restrict__ out)                   // [M][512] f32
{
    const int lane = threadIdx.x & 63;
    const int wave = threadIdx.x >> 6;
    const int m    = lane & 15;
    const int quad = lane >> 4;

    const long r0 = ((long)blockIdx.x * 4 + wave) * 32;

    bf16x8 bfrag[2][4];                         // hs rows as second operand
    #pragma unroll
    for (int rt = 0; rt < 2; rt++) {
        #pragma unroll
        for (int q = 0; q < 4; q++) {
            const bf16x8* p = (const bf16x8*)
                (hsb + (r0 + rt * 16 + m) * HID + q * 32 + quad * 8);
            bfrag[rt][q] = __builtin_nontemporal_load(p);   // single-use rows
        }
    }

    for (int ct2 = 0; ct2 < 16; ct2++) {
        const int ct0 = 2 * ct2;
        f32x4 acc00 = {0.f, 0.f, 0.f, 0.f};
        f32x4 acc01 = {0.f, 0.f, 0.f, 0.f};
        f32x4 acc10 = {0.f, 0.f, 0.f, 0.f};
        f32x4 acc11 = {0.f, 0.f, 0.f, 0.f};
        #pragma unroll
        for (int q = 0; q < 4; q++) {
            bf16x8 aw0 = *(const bf16x8*)(wfrag + (((ct0)     * 4 + q) * 64 + lane) * 8);
            bf16x8 aw1 = *(const bf16x8*)(wfrag + (((ct0 + 1) * 4 + q) * 64 + lane) * 8);
            acc00 = __builtin_amdgcn_mfma_f32_16x16x32_bf16(aw0, bfrag[0][q], acc00, 0, 0, 0);
            acc01 = __builtin_amdgcn_mfma_f32_16x16x32_bf16(aw1, bfrag[0][q], acc01, 0, 0, 0);
            acc10 = __builtin_amdgcn_mfma_f32_16x16x32_bf16(aw0, bfrag[1][q], acc10, 0, 0, 0);
            acc11 = __builtin_amdgcn_mfma_f32_16x16x32_bf16(aw1, bfrag[1][q], acc11, 0, 0, 0);
        }
        const int n0 = ct0 * 16 + quad * 4;
        const f32x4 bias0 = *(const f32x4*)&fc_b[n0];
        const f32x4 bias1 = *(const f32x4*)&fc_b[n0 + 16];
        float* row0 = &out[(r0 + m) * NOUT];
        float* row1 = &out[(r0 + 16 + m) * NOUT];
        f32x4 o;
        o = acc00 + bias0;
        __builtin_nontemporal_store(o, (f32x4*)&row0[n0]);
        o = acc01 + bias1;
        __builtin_nontemporal_store(o, (f32x4*)&row0[n0 + 16]);
        o = acc10 + bias0;
        __builtin_nontemporal_store(o, (f32x4*)&row1[n0]);
        o = acc11 + bias1;
        __builtin_nontemporal_store(o, (f32x4*)&row1[n0 + 16]);
    }
}

extern "C" void kernel_launch(void* const* d_in, const int* in_sizes, int n_in,
                              void* d_out, int out_size, void* d_ws, size_t ws_size,
                              hipStream_t stream) {
    const float* latent = (const float*)d_in[0];   // (64,128)
    const float* W_hh   = (const float*)d_in[1];   // (384,128)
    const float* b_ih   = (const float*)d_in[2];   // (384,)
    const float* b_hh   = (const float*)d_in[3];   // (384,)
    const float* fc_W   = (const float*)d_in[4];   // (512,128)
    const float* fc_b   = (const float*)d_in[5];   // (512,)
    float* out = (float*)d_out;                    // (64,2048,512)

    __hip_bfloat16* hsb   = (__hip_bfloat16*)d_ws;                   // 33.5 MB
    __hip_bfloat16* wfrag = (__hip_bfloat16*)((char*)d_ws + (size_t)BATCH * SEQ * HID * 2);

    wprep<<<256, 256, 0, stream>>>(fc_W, wfrag);
    gru_seq<<<8, 512, 0, stream>>>(latent, W_hh, b_ih, b_hh, hsb);

    const int M = BATCH * SEQ;                     // 131072
    proj_mfma<<<M / 128, 256, 0, stream>>>(hsb, wfrag, fc_b, out);
}

// Round 7
// 1682.165 us; speedup vs baseline: 1.0435x; 1.0111x over previous
//
#include <hip/hip_runtime.h>
#include <hip/hip_bf16.h>

#define HID 128
#define SEQ 2048
#define BATCH 64
#define NOUT 512

typedef __attribute__((ext_vector_type(8))) short bf16x8;
typedef __attribute__((ext_vector_type(4))) float f32x4;

__device__ __forceinline__ short f2bf(float f) {
    unsigned u = __float_as_uint(f);
    unsigned r = u + 0x7fffu + ((u >> 16) & 1u);   // RNE
    return (short)(r >> 16);
}

__device__ __forceinline__ float fast_sigmoid(float x) {
    return 1.0f / (1.0f + __expf(-x));
}

__device__ __forceinline__ float fast_tanh(float x) {
    return 1.0f - 2.0f / (__expf(2.0f * x) + 1.0f);
}

// lane ^ 8 within each 16-lane row: DPP ROW_ROR:8. Pure VALU (~2cyc);
// replaced DS-pipe shuffles in round 5/6 (verified: conflicts -> 0).
__device__ __forceinline__ float dpp_ror8(float x) {
    int y = __builtin_amdgcn_update_dpp(0, __builtin_bit_cast(int, x),
                                        0x128, 0xF, 0xF, true);
    return __builtin_bit_cast(float, y);
}

// One W_hh MFMA A-fragment: rows = 16T + rr, k-slice = kcol..kcol+7 (bf16)
__device__ __forceinline__ bf16x8 load_wfrag(const float* __restrict__ W_hh,
                                             int row, int kcol) {
    const float* wp = W_hh + (size_t)row * HID + kcol;
    float4 x = *(const float4*)wp;
    float4 y = *(const float4*)(wp + 4);
    bf16x8 f;
    f[0] = f2bf(x.x); f[1] = f2bf(x.y); f[2] = f2bf(x.z); f[3] = f2bf(x.w);
    f[4] = f2bf(y.x); f[5] = f2bf(y.y); f[6] = f2bf(y.z); f[7] = f2bf(y.w);
    return f;
}

// ---------------------------------------------------------------------------
// MFMA GRU recurrence. 8 blocks x 8 batches; 512 threads = 8 waves.
// ROUND-7 FIX: every prior round had FETCH_SIZE ~820MB = 50KB/block-step =
// the full W-fragment set RELOADED FROM SCRATCH EVERY STEP (VGPR_Count
// 60-76 in all rounds: allocator targeted full occupancy and spilled the
// weight arrays; the scratch reload's memory latency sat on the critical
// path every timestep -- the ~1500cyc/step floor that made all in-loop
// optimizations nearly neutral).
//   1. __launch_bounds__(512, 1): 1 wave/EU minimum -> 512-VGPR budget.
//   2. W fragments as 12 NAMED bf16x8 variables (no array -> no chance of
//      scratch lowering).
// Rest is the harness-verified round-6 body (swizzled LDS, DPP rebalance,
// masked H reads, bias-seeded accumulators, raw barrier, nt-store proj).
// ---------------------------------------------------------------------------
__global__ __launch_bounds__(512, 1) void gru_seq(
    const float* __restrict__ latent,   // [BATCH][HID]
    const float* __restrict__ W_hh,     // [3*HID][HID]
    const float* __restrict__ b_ih,     // [3*HID]
    const float* __restrict__ b_hh,     // [3*HID]
    __hip_bfloat16* __restrict__ hs)    // [BATCH][SEQ][HID]  (bf16)
{
    const int tid  = threadIdx.x;          // 0..511
    const int j    = tid >> 6;             // wave 0..7 -> n-tiles {j,j+8,j+16}
    const int lane = tid & 63;
    const int rr   = lane & 15;            // operand 16-axis / D batch col
    const int g    = lane >> 4;            // 0..3
    const int hi   = (lane >> 3) & 1;      // upper half of 16-group
    const int br   = rr & 7;               // batch row 0..7
    const int h0   = 16 * j + 4 * g + 2 * hi;  // this lane's 2 h columns
    const int n0l  = 16 * j + 4 * g;           // this lane's 4 gate rows

    // [2 buffers][16 rows][128 cols] bf16, 16B-block swizzled within rows
    __shared__ __align__(16) __hip_bfloat16 Hl[2][2048];

    // ---- W fragments: 12 NAMED registers (row-4..6 spill fix) ----
    const int wrow = j * 16 + rr;          // r-gate tile row; z: +128; n: +256
    bf16x8 wr0 = load_wfrag(W_hh, wrow,       0 * 32 + g * 8);
    bf16x8 wr1 = load_wfrag(W_hh, wrow,       1 * 32 + g * 8);
    bf16x8 wr2 = load_wfrag(W_hh, wrow,       2 * 32 + g * 8);
    bf16x8 wr3 = load_wfrag(W_hh, wrow,       3 * 32 + g * 8);
    bf16x8 wz0 = load_wfrag(W_hh, wrow + 128, 0 * 32 + g * 8);
    bf16x8 wz1 = load_wfrag(W_hh, wrow + 128, 1 * 32 + g * 8);
    bf16x8 wz2 = load_wfrag(W_hh, wrow + 128, 2 * 32 + g * 8);
    bf16x8 wz3 = load_wfrag(W_hh, wrow + 128, 3 * 32 + g * 8);
    bf16x8 wn0 = load_wfrag(W_hh, wrow + 256, 0 * 32 + g * 8);
    bf16x8 wn1 = load_wfrag(W_hh, wrow + 256, 1 * 32 + g * 8);
    bf16x8 wn2 = load_wfrag(W_hh, wrow + 256, 2 * 32 + g * 8);
    bf16x8 wn3 = load_wfrag(W_hh, wrow + 256, 3 * 32 + g * 8);

    // ---- accumulator bias seeds (lane's 4 gate rows n0l..n0l+3) ----
    f32x4 seedR, seedZ, seedN;
    {
        float4 bi = *(const float4*)&b_ih[n0l];
        float4 bh = *(const float4*)&b_hh[n0l];
        seedR[0] = bi.x + bh.x; seedR[1] = bi.y + bh.y;
        seedR[2] = bi.z + bh.z; seedR[3] = bi.w + bh.w;
        bi = *(const float4*)&b_ih[HID + n0l];
        bh = *(const float4*)&b_hh[HID + n0l];
        seedZ[0] = bi.x + bh.x; seedZ[1] = bi.y + bh.y;
        seedZ[2] = bi.z + bh.z; seedZ[3] = bi.w + bh.w;
        bh = *(const float4*)&b_hh[2 * HID + n0l];
        seedN[0] = bh.x; seedN[1] = bh.y; seedN[2] = bh.z; seedN[3] = bh.w;
    }
    const float2 bin2 = *(const float2*)&b_ih[2 * HID + h0];
    const float bn0 = bin2.x, bn1 = bin2.y;

    // ---- swizzled LDS element offsets (lane constants, round-4-proven) ----
    const int re0 = rr * 128 + (((0 * 4 + g) ^ (rr & 7)) << 3);
    const int re1 = rr * 128 + (((1 * 4 + g) ^ (rr & 7)) << 3);
    const int re2 = rr * 128 + (((2 * 4 + g) ^ (rr & 7)) << 3);
    const int re3 = rr * 128 + (((3 * 4 + g) ^ (rr & 7)) << 3);
    const int we = br * 128 + ((((2 * j) + (g >> 1)) ^ br) << 3)
                 + 4 * (g & 1) + 2 * hi;

    // ---- init: hold regs + H buffer 0 ----
    const int batch = blockIdx.x * 8 + br;
    float2 h02 = *(const float2*)&latent[batch * HID + h0];
    float hold0 = h02.x, hold1 = h02.y;
    {
        unsigned v = (unsigned short)f2bf(hold0)
                   | ((unsigned)(unsigned short)f2bf(hold1) << 16);
        *(unsigned*)&Hl[0][we] = v;
    }
    __syncthreads();

    __hip_bfloat16* op = hs + ((size_t)batch * SEQ) * HID + h0;

    bf16x8 hf0 = {}, hf1 = {}, hf2 = {}, hf3 = {};
    int p = 0;
    for (int t = 0; t < SEQ; t++) {
        // H fragments: rows 0-7 only (rr>=8 lanes feed discarded D columns)
        const __hip_bfloat16* hb = &Hl[p][0];
        if (rr < 8) {
            hf0 = *(const bf16x8*)&hb[re0];
            hf1 = *(const bf16x8*)&hb[re1];
            hf2 = *(const bf16x8*)&hb[re2];
            hf3 = *(const bf16x8*)&hb[re3];
        }

        f32x4 a0 = seedR;   // r-gate tile j      (bias pre-seeded)
        f32x4 a1 = seedZ;   // z-gate tile j+8
        f32x4 a2 = seedN;   // n-gate tile j+16   (b_hh part)
        a0 = __builtin_amdgcn_mfma_f32_16x16x32_bf16(wr0, hf0, a0, 0, 0, 0);
        a1 = __builtin_amdgcn_mfma_f32_16x16x32_bf16(wz0, hf0, a1, 0, 0, 0);
        a2 = __builtin_amdgcn_mfma_f32_16x16x32_bf16(wn0, hf0, a2, 0, 0, 0);
        a0 = __builtin_amdgcn_mfma_f32_16x16x32_bf16(wr1, hf1, a0, 0, 0, 0);
        a1 = __builtin_amdgcn_mfma_f32_16x16x32_bf16(wz1, hf1, a1, 0, 0, 0);
        a2 = __builtin_amdgcn_mfma_f32_16x16x32_bf16(wn1, hf1, a2, 0, 0, 0);
        a0 = __builtin_amdgcn_mfma_f32_16x16x32_bf16(wr2, hf2, a0, 0, 0, 0);
        a1 = __builtin_amdgcn_mfma_f32_16x16x32_bf16(wz2, hf2, a1, 0, 0, 0);
        a2 = __builtin_amdgcn_mfma_f32_16x16x32_bf16(wn2, hf2, a2, 0, 0, 0);
        a0 = __builtin_amdgcn_mfma_f32_16x16x32_bf16(wr3, hf3, a0, 0, 0, 0);
        a1 = __builtin_amdgcn_mfma_f32_16x16x32_bf16(wz3, hf3, a1, 0, 0, 0);
        a2 = __builtin_amdgcn_mfma_f32_16x16x32_bf16(wn3, hf3, a2, 0, 0, 0);

        // rebalance: hi half adopts regs 2,3 from lane^8 -- pure VALU DPP
        float s00 = dpp_ror8(a0[2]), s01 = dpp_ror8(a0[3]);
        float s10 = dpp_ror8(a1[2]), s11 = dpp_ror8(a1[3]);
        float s20 = dpp_ror8(a2[2]), s21 = dpp_ror8(a2[3]);
        float gr0 = hi ? s00 : a0[0], gr1 = hi ? s01 : a0[1];
        float gz0 = hi ? s10 : a1[0], gz1 = hi ? s11 : a1[1];
        float gn0 = hi ? s20 : a2[0], gn1 = hi ? s21 : a2[1];

        // activations (biases already folded into the accumulators)
        float r0 = fast_sigmoid(gr0);
        float z0 = fast_sigmoid(gz0);
        float n0 = fast_tanh(bn0 + r0 * gn0);
        float hn0 = (1.0f - z0) * n0 + z0 * hold0;
        hold0 = hn0;
        float r1 = fast_sigmoid(gr1);
        float z1 = fast_sigmoid(gz1);
        float n1 = fast_tanh(bn1 + r1 * gn1);
        float hn1 = (1.0f - z1) * n1 + z1 * hold1;
        hold1 = hn1;

        unsigned v = (unsigned short)f2bf(hn0)
                   | ((unsigned)(unsigned short)f2bf(hn1) << 16);
        *(unsigned*)&Hl[p ^ 1][we] = v;    // next step's H (swizzled slot)
        *(unsigned*)op = v;                // history output (not drained)
        op += HID;

        // LDS-only drain + raw barrier: global stores stay in flight
        asm volatile("s_waitcnt lgkmcnt(0)" ::: "memory");
        __builtin_amdgcn_s_barrier();
        asm volatile("" ::: "memory");
        p ^= 1;
    }
}

// ---------------------------------------------------------------------------
// Repack fc_W (f32 [512][128]) into bf16 MFMA fragment order:
//   wfrag[((ct*4 + q)*64 + lane)*8 + j] = bf16(fc_W[ct*16 + (lane&15)]
//                                                  [q*32 + (lane>>4)*8 + j])
// ---------------------------------------------------------------------------
__global__ void wprep(const float* __restrict__ fc_W,
                      __hip_bfloat16* __restrict__ wfrag)
{
    int t = blockIdx.x * 256 + threadIdx.x;      // 0..65535
    int j    = t & 7;
    int lane = (t >> 3) & 63;
    int q    = (t >> 9) & 3;
    int ct   = t >> 11;
    int n = ct * 16 + (lane & 15);
    int k = q * 32 + (lane >> 4) * 8 + j;
    unsigned short v = (unsigned short)f2bf(fc_W[n * HID + k]);
    wfrag[t] = __builtin_bit_cast(__hip_bfloat16, v);
}

// ---------------------------------------------------------------------------
// Projection: out[row][o] = sum_k hs[row][k] * fc_W[o][k] + fc_b[o]
// M = 131072, N = 512, K = 128. bf16 MFMA 16x16x32, operand-swapped.
// Nontemporal stores/loads (round-6, passing).
// ---------------------------------------------------------------------------
__global__ __launch_bounds__(256) void proj_mfma(
    const __hip_bfloat16* __restrict__ hsb,    // [M][128] bf16
    const __hip_bfloat16* __restrict__ wfrag,  // fragment-ordered [32][4][64][8]
    const float* __restrict__ fc_b,            // [512]
    float* __restrict__ out)                   // [M][512] f32
{
    const int lane = threadIdx.x & 63;
    const int wave = threadIdx.x >> 6;
    const int m    = lane & 15;
    const int quad = lane >> 4;

    const long r0 = ((long)blockIdx.x * 4 + wave) * 32;

    bf16x8 bfrag[2][4];                         // hs rows as second operand
    #pragma unroll
    for (int rt = 0; rt < 2; rt++) {
        #pragma unroll
        for (int q = 0; q < 4; q++) {
            const bf16x8* p = (const bf16x8*)
                (hsb + (r0 + rt * 16 + m) * HID + q * 32 + quad * 8);
            bfrag[rt][q] = __builtin_nontemporal_load(p);   // single-use rows
        }
    }

    for (int ct2 = 0; ct2 < 16; ct2++) {
        const int ct0 = 2 * ct2;
        f32x4 acc00 = {0.f, 0.f, 0.f, 0.f};
        f32x4 acc01 = {0.f, 0.f, 0.f, 0.f};
        f32x4 acc10 = {0.f, 0.f, 0.f, 0.f};
        f32x4 acc11 = {0.f, 0.f, 0.f, 0.f};
        #pragma unroll
        for (int q = 0; q < 4; q++) {
            bf16x8 aw0 = *(const bf16x8*)(wfrag + (((ct0)     * 4 + q) * 64 + lane) * 8);
            bf16x8 aw1 = *(const bf16x8*)(wfrag + (((ct0 + 1) * 4 + q) * 64 + lane) * 8);
            acc00 = __builtin_amdgcn_mfma_f32_16x16x32_bf16(aw0, bfrag[0][q], acc00, 0, 0, 0);
            acc01 = __builtin_amdgcn_mfma_f32_16x16x32_bf16(aw1, bfrag[0][q], acc01, 0, 0, 0);
            acc10 = __builtin_amdgcn_mfma_f32_16x16x32_bf16(aw0, bfrag[1][q], acc10, 0, 0, 0);
            acc11 = __builtin_amdgcn_mfma_f32_16x16x32_bf16(aw1, bfrag[1][q], acc11, 0, 0, 0);
        }
        const int n0 = ct0 * 16 + quad * 4;
        const f32x4 bias0 = *(const f32x4*)&fc_b[n0];
        const f32x4 bias1 = *(const f32x4*)&fc_b[n0 + 16];
        float* row0 = &out[(r0 + m) * NOUT];
        float* row1 = &out[(r0 + 16 + m) * NOUT];
        f32x4 o;
        o = acc00 + bias0;
        __builtin_nontemporal_store(o, (f32x4*)&row0[n0]);
        o = acc01 + bias1;
        __builtin_nontemporal_store(o, (f32x4*)&row0[n0 + 16]);
        o = acc10 + bias0;
        __builtin_nontemporal_store(o, (f32x4*)&row1[n0]);
        o = acc11 + bias1;
        __builtin_nontemporal_store(o, (f32x4*)&row1[n0 + 16]);
    }
}

extern "C" void kernel_launch(void* const* d_in, const int* in_sizes, int n_in,
                              void* d_out, int out_size, void* d_ws, size_t ws_size,
                              hipStream_t stream) {
    const float* latent = (const float*)d_in[0];   // (64,128)
    const float* W_hh   = (const float*)d_in[1];   // (384,128)
    const float* b_ih   = (const float*)d_in[2];   // (384,)
    const float* b_hh   = (const float*)d_in[3];   // (384,)
    const float* fc_W   = (const float*)d_in[4];   // (512,128)
    const float* fc_b   = (const float*)d_in[5];   // (512,)
    float* out = (float*)d_out;                    // (64,2048,512)

    __hip_bfloat16* hsb   = (__hip_bfloat16*)d_ws;                   // 33.5 MB
    __hip_bfloat16* wfrag = (__hip_bfloat16*)((char*)d_ws + (size_t)BATCH * SEQ * HID * 2);

    wprep<<<256, 256, 0, stream>>>(fc_W, wfrag);
    gru_seq<<<8, 512, 0, stream>>>(latent, W_hh, b_ih, b_hh, hsb);

    const int M = BATCH * SEQ;                     // 131072
    proj_mfma<<<M / 128, 256, 0, stream>>>(hsb, wfrag, fc_b, out);
}